// Round 12
// baseline (101.328 us; speedup 1.0000x reference)
//
#include <hip/hip_runtime.h>
#include <hip/hip_bf16.h>

// B=64, M=16, T=2048, L=64, K=32, N=1985
#define B_ 64
#define M_ 16
#define T_ 2048
#define L_ 64
#define K_ 32
#define N_ (T_ - L_ + 1)   // 1985
#define NQP 512            // padded n-quad rows per m (covers last tile, no guards)
#define TN 64              // n-positions per block
#define NTH 256            // 4 waves: wave w owns n-subtile [16w,16w+16), both k-tiles
#define XROW 144           // per-plane row elems; j<=123 needed. 72 dw == 8 (mod 32)
                           // -> planes at bank offs {0,8,16,24}: uniform 4/bank (floor).
#define STSTR 72           // st row stride elems (16B-aligned b128 reads)
#define SQSTR 64           // sqw row stride (reads are q-only broadcasts)

typedef __attribute__((ext_vector_type(8))) short bf16x8;
typedef __attribute__((ext_vector_type(4))) float f32x4;

__device__ __forceinline__ unsigned short f2bf(float f) {
    __hip_bfloat16 h = __float2bfloat16(f);
    return __builtin_bit_cast(unsigned short, h);
}

// pen_t[m][nq][k][r] = elu(-pmap[k][m][clamp(4*nq+r)]) + 2   (fp32)
// Transposed so a quad's 16 lanes (k=0..15) load 256B CONTIGUOUS per float4 instr
// (R11 layout: 16 lanes strided 127KB -> 32 quarter-used lines per load).
// Also: ss[k] = sum_l shp[k][l]^2; out[] = +inf.
__global__ void pen_init_kernel(const float* __restrict__ pmap,
                                const float* __restrict__ shp,
                                float* __restrict__ pen_t,
                                float* __restrict__ ss_ws,
                                unsigned* __restrict__ out) {
    const int gid = blockIdx.x * 256 + threadIdx.x;   // 0 .. M_*NQP*K_-1 (262144)
    if (gid < B_ * K_) out[gid] = 0x7F800000u;  // +inf
    if (gid < K_) {
        float s = 0.f;
        for (int l = 0; l < L_; ++l) { float v = shp[gid * L_ + l]; s = fmaf(v, v, s); }
        ss_ws[gid] = s;
    }
    if (gid < M_ * NQP * K_) {
        const int m  = gid >> 14;            // / (NQP*K_)
        const int rem = gid & 16383;
        const int nq = rem >> 5;             // / K_
        const int k  = rem & 31;
        const float* src = pmap + ((size_t)k * M_ + m) * N_;
        float4 r;
        float* pr = (float*)&r;
#pragma unroll
        for (int i = 0; i < 4; ++i) {
            int n = 4 * nq + i; if (n >= N_) n = N_ - 1;   // clamp: masked at min
            const float p = src[n];
            pr[i] = (p < 0.f) ? (2.f - p) : (__expf(-p) + 1.f);
        }
        *(float4*)(pen_t + (size_t)gid * 4) = r;
    }
}

__global__ __launch_bounds__(NTH, 2)
void shapelet_mfma_kernel(const float* __restrict__ x,
                          const float* __restrict__ shp,
                          const float* __restrict__ pen_t,
                          const float* __restrict__ ss_ws,
                          unsigned* __restrict__ out) {
    // LDS: 18432 + 4608 + 4096 = 27136 B -> 6 blocks/CU
    // xbuf4[m][s][j] = bf16(x[b][m][n0 + j + s]) : 4 shifted planes so every
    // A-fragment (elem start o = 16w+8q+rl+32h, o%4 == rl%4) is one
    // ds_read2_b64 from plane s=rl&3 at 4-aligned e = o - s. Zero extract VALU.
    __shared__ __align__(16) unsigned short xbuf4[M_][4][XROW];
    __shared__ __align__(16) unsigned short st[K_][STSTR];   // shapelets bf16
    __shared__ __align__(16) float sqw[M_][SQSTR];           // fp32 sliding sum x^2

    const int tid = threadIdx.x;
    const int n0 = blockIdx.x * TN;
    const int b  = blockIdx.y;
    const bool fast = (n0 + 128 <= T_);   // false only for last tile (n0=1984)

    // ---- stage x as 4 shifted bf16 planes: j4 = 0..120 -> j coverage 0..123 ----
    const float* xb = x + ((size_t)b * M_) * T_ + n0;
    for (int g = tid; g < M_ * 31; g += NTH) {
        const int m = g / 31, j4 = (g - m * 31) * 4;     // j4 in {0,4,...,120}
        const float* src = xb + m * T_ + j4;
        float h[8];
        if (fast) {
            float4 v0 = *(const float4*)src;
            float4 v1 = *(const float4*)(src + 4);
            h[0] = v0.x; h[1] = v0.y; h[2] = v0.z; h[3] = v0.w;
            h[4] = v1.x; h[5] = v1.y; h[6] = v1.z; h[7] = v1.w;
        } else {
#pragma unroll
            for (int i = 0; i < 8; ++i)
                h[i] = (n0 + j4 + i < T_) ? src[i] : 0.f;
        }
        unsigned short hb[8];
#pragma unroll
        for (int i = 0; i < 8; ++i) hb[i] = f2bf(h[i]);
#pragma unroll
        for (int s = 0; s < 4; ++s) {
            ushort4 sv = { hb[s], hb[s + 1], hb[s + 2], hb[s + 3] };
            *(ushort4*)&xbuf4[m][s][j4] = sv;
        }
    }
    // ---- stage shapelets st[k][l] bf16 ----
    for (int i = tid; i < K_ * 16; i += NTH) {
        const int k = i >> 4, l4 = (i & 15) * 4;
        float4 v = *(const float4*)(shp + k * L_ + l4);
        ushort4 sv = { f2bf(v.x), f2bf(v.y), f2bf(v.z), f2bf(v.w) };
        *(ushort4*)&st[k][l4] = sv;
    }
    // ---- sqw fp32 sliding window: 8 threads per m, 8 n each (threads 0..127) ----
    if (tid < M_ * 8) {
        const int m = tid >> 3, j0 = (tid & 7) * 8;
        const float* xr = x + ((size_t)b * M_ + m) * T_ + n0;
        float s = 0.f;
        if (fast) {
#pragma unroll
            for (int qd = 0; qd < 16; ++qd) {
                float4 v = *(const float4*)(xr + j0 + qd * 4);
                s = fmaf(v.x, v.x, s); s = fmaf(v.y, v.y, s);
                s = fmaf(v.z, v.z, s); s = fmaf(v.w, v.w, s);
            }
            sqw[m][j0] = s;
#pragma unroll
            for (int d = 1; d < 8; ++d) {
                float a = xr[j0 + d + L_ - 1], r = xr[j0 + d - 1];
                s += a * a - r * r;
                sqw[m][j0 + d] = s;
            }
        } else {
            for (int l = 0; l < L_; ++l) {
                float v = (n0 + j0 + l < T_) ? xr[j0 + l] : 0.f;
                s = fmaf(v, v, s);
            }
            sqw[m][j0] = s;
            for (int d = 1; d < 8; ++d) {
                float a = (n0 + j0 + d + L_ - 1 < T_) ? xr[j0 + d + L_ - 1] : 0.f;
                float r = (n0 + j0 + d - 1 < T_) ? xr[j0 + d - 1] : 0.f;
                s += a * a - r * r;
                sqw[m][j0 + d] = s;
            }
        }
    }
    __syncthreads();

    // ---- per-lane MFMA coordinates ----
    const int lane = tid & 63;
    const int w  = tid >> 6;       // wave -> n-subtile [16w, 16w+16)
    const int rl = lane & 15;      // A-row (n within subtile) / B-col (k within tile)
    const int q  = lane >> 4;      // quad
    const int sp = rl & 3;                          // shift plane
    const int e0 = 16 * w + 8 * q + (rl & ~3);      // 4-aligned elem base (max 84)
    const int eq = e0 >> 2;                         // uint2 index (max 21; +9 <= 30 < 36)
    const int nrow = n0 + 16 * w + 4 * q;           // lane's 4 output rows: nrow + reg

    // b_frags (registers, whole kernel): st[16t+rl][8q+32h .. +7]
    bf16x8 bfr[2][2];
#pragma unroll
    for (int t = 0; t < 2; ++t)
#pragma unroll
        for (int h = 0; h < 2; ++h)
            bfr[t][h] = *(const bf16x8*)&st[16 * t + rl][8 * q + 32 * h];

    const float ssk0 = ss_ws[rl], ssk1 = ss_ws[16 + rl];

    // pen_t[m][nq][k][r]: quad-contiguous 256B loads; no bounds guards (NQP pad)
    const int nq_l = (n0 >> 2) + 4 * w + q;
    const float* pt0 = pen_t + (((size_t)nq_l) * K_ + rl) * 4;   // m=0, k=rl
    // m-step = NQP*K_*4 = 65536 floats; k+16 -> +64 floats

    f32x4 wd0 = (f32x4)0.f, wd1 = (f32x4)0.f;
    const f32x4 zero = (f32x4)0.f;

#pragma unroll 2
    for (int m = 0; m < M_; ++m) {
        // ---- pen fp32 for this m: fully coalesced float4 loads ----
        float4 p0 = *(const float4*)(pt0 + (size_t)m * (NQP * K_ * 4));
        float4 p1 = *(const float4*)(pt0 + (size_t)m * (NQP * K_ * 4) + 64);

        // ---- A-frags: 8B-aligned LDS read pairs, no extract VALU ----
        const uint2* prow = (const uint2*)&xbuf4[m][sp][0];  // row 16B-aligned
        uint2 lo0 = prow[eq],     hi0 = prow[eq + 1];        // frag h=0
        uint2 lo1 = prow[eq + 8], hi1 = prow[eq + 9];        // frag h=1 (+32 elem)
        union { uint2 u2[2]; bf16x8 v; } fa0, fa1;
        fa0.u2[0] = lo0; fa0.u2[1] = hi0;
        fa1.u2[0] = lo1; fa1.u2[1] = hi1;

        f32x4 c0_ = __builtin_amdgcn_mfma_f32_16x16x32_bf16(fa0.v, bfr[0][0], zero, 0, 0, 0);
        c0_       = __builtin_amdgcn_mfma_f32_16x16x32_bf16(fa1.v, bfr[0][1], c0_, 0, 0, 0);
        f32x4 c1_ = __builtin_amdgcn_mfma_f32_16x16x32_bf16(fa0.v, bfr[1][0], zero, 0, 0, 0);
        c1_       = __builtin_amdgcn_mfma_f32_16x16x32_bf16(fa1.v, bfr[1][1], c1_, 0, 0, 0);

        f32x4 sq = *(const f32x4*)&sqw[m][16 * w + 4 * q];
        const float pe0[4] = { p0.x, p0.y, p0.z, p0.w };
        const float pe1[4] = { p1.x, p1.y, p1.z, p1.w };
#pragma unroll
        for (int r = 0; r < 4; ++r) {
            float t0v = fmaf(-2.f, c0_[r], sq[r] + ssk0);
            wd0[r] = fmaf(pe0[r], t0v, wd0[r]);
            float t1v = fmaf(-2.f, c1_[r], sq[r] + ssk1);
            wd1[r] = fmaf(pe1[r], t1v, wd1[r]);
        }
    }

    // ---- min over lane's 4 rows -> across quads -> atomicMin per (b,k) ----
#pragma unroll
    for (int t = 0; t < 2; ++t) {
        float lmin = __int_as_float(0x7F800000);
        const f32x4& wdv = t ? wd1 : wd0;
#pragma unroll
        for (int r = 0; r < 4; ++r) {
            if (nrow + r < N_) lmin = fminf(lmin, wdv[r]);
        }
        lmin = fminf(lmin, __shfl_xor(lmin, 16));
        lmin = fminf(lmin, __shfl_xor(lmin, 32));
        if (q == 0) {
            atomicMin(out + (size_t)b * K_ + 16 * t + rl,
                      __float_as_uint(fmaxf(lmin, 0.f)));
        }
    }
}

extern "C" void kernel_launch(void* const* d_in, const int* in_sizes, int n_in,
                              void* d_out, int out_size, void* d_ws, size_t ws_size,
                              hipStream_t stream) {
    const float* x    = (const float*)d_in[0];   // (B, M, T)
    const float* shp  = (const float*)d_in[1];   // (K, L)
    const float* pmap = (const float*)d_in[2];   // (K, M, N)
    unsigned* out = (unsigned*)d_out;            // (B, K) float bits
    float* pen_t = (float*)d_ws;                 // (M, NQP, K, 4) fp32, 4 MB
    float* ss_ws = pen_t + (size_t)M_ * NQP * K_ * 4;

    const int work = M_ * NQP * K_;              // 262144 threads
    pen_init_kernel<<<dim3(work / 256), dim3(256), 0, stream>>>(
        pmap, shp, pen_t, ss_ws, out);

    dim3 grid((N_ + TN - 1) / TN, B_);           // 32 x 64 = 2048 blocks
    shapelet_mfma_kernel<<<grid, dim3(NTH), 0, stream>>>(x, shp, pen_t, ss_ws, out);
}